// Round 16
// baseline (1168.782 us; speedup 1.0000x reference)
//
#include <hip/hip_runtime.h>
#include <math.h>

#define B_ROWS 8192
#define P_KEYS 2048
#define D_DIM  768
#define L_LEN  5
#define K_SEL  5
#define EPSV   1e-8f

#define RBLK   128                 // rows per block
#define CBLK   128                 // cols per block
#define NCB2   (P_KEYS / CBLK)     // 16 col blocks
#define KC     32                  // MFMA K per stage
#define NKC    (D_DIM / KC)        // 24
#define NCSET  (NCB2 * 2)          // 32 candidate sets per row (64-col granularity)
#define NCAND  (NCSET * K_SEL)     // 160 candidates per row
#define NRESC  16                  // exact-rescored candidates per row

typedef _Float16 half8  __attribute__((ext_vector_type(8)));
typedef _Float16 half4v __attribute__((ext_vector_type(4)));
typedef float    f32x4  __attribute__((ext_vector_type(4)));

// sorted ascending (v[0] best). Tie-break: lower index wins (jax top_k semantics).
__device__ inline void insert5(float (&v)[K_SEL], int (&ix)[K_SEL], float nv, int ni) {
    if (nv < v[K_SEL-1] || (nv == v[K_SEL-1] && ni < ix[K_SEL-1])) {
        v[K_SEL-1] = nv; ix[K_SEL-1] = ni;
        #pragma unroll
        for (int j = K_SEL-1; j > 0; --j) {
            bool sw = (v[j] < v[j-1]) || (v[j] == v[j-1] && ix[j] < ix[j-1]);
            if (sw) {
                float tv = v[j]; v[j] = v[j-1]; v[j-1] = tv;
                int   ti = ix[j]; ix[j] = ix[j-1]; ix[j-1] = ti;
            }
        }
    }
}

// One wave per row. Keys: -> kn (fp32 normalized, exact-rescore input) and
// kh (fp16). X rows: -> inv_x AND xh = fp16(x * inv_x) — precomputed ONCE
// (r15 converted the same product per column-block, 32x redundantly; identical
// arithmetic, so approx candidates are unchanged).
__global__ __launch_bounds__(256)
void norm_kernel(const float* __restrict__ x, const float* __restrict__ pk,
                 float* __restrict__ kn, _Float16* __restrict__ kh,
                 _Float16* __restrict__ xh, float* __restrict__ inv_x) {
    int wave = (blockIdx.x * blockDim.x + threadIdx.x) >> 6;
    int lane = threadIdx.x & 63;
    bool is_key = (wave < P_KEYS);
    int row = is_key ? wave : wave - P_KEYS;
    const float* src = is_key ? (pk + (size_t)row * D_DIM) : (x + (size_t)row * D_DIM);

    const float4* s4 = (const float4*)src;
    float4 v[3];
    float s = 0.f;
    #pragma unroll
    for (int i = 0; i < 3; ++i) {
        v[i] = s4[lane + 64 * i];
        s += v[i].x * v[i].x + v[i].y * v[i].y + v[i].z * v[i].z + v[i].w * v[i].w;
    }
    #pragma unroll
    for (int off = 32; off; off >>= 1) s += __shfl_xor(s, off, 64);
    float inv = 1.0f / fmaxf(sqrtf(s), EPSV);

    if (is_key) {
        float4* d4 = (float4*)(kn + (size_t)row * D_DIM);
        #pragma unroll
        for (int i = 0; i < 3; ++i) {
            float4 w = v[i];
            w.x *= inv; w.y *= inv; w.z *= inv; w.w *= inv;
            d4[lane + 64 * i] = w;
            half4v h = { (_Float16)w.x, (_Float16)w.y, (_Float16)w.z, (_Float16)w.w };
            *(half4v*)(kh + (size_t)row * D_DIM + (lane + 64 * i) * 4) = h;
        }
    } else {
        #pragma unroll
        for (int i = 0; i < 3; ++i) {
            float4 w = v[i];
            half4v h = { (_Float16)(w.x * inv), (_Float16)(w.y * inv),
                         (_Float16)(w.z * inv), (_Float16)(w.w * inv) };
            *(half4v*)(xh + (size_t)row * D_DIM + (lane + 64 * i) * 4) = h;
        }
        if (lane == 0) inv_x[row] = inv;
    }
}

// Approx pass v2: pure-fp16 MFMA GEMM of x_hat . k_hat^T.
// grid = (NCB2=16, B_ROWS/RBLK=64) = 1024 blocks, block 256 (4 waves).
// Each wave owns a 64x64 tile (2x2 wave grid): 4 A-frags x 4 B-frags ->
// 16 MFMAs per 8 ds_read_b128 (4x the MFMA:DS ratio of r15, which sat at
// MfmaUtil 2.3% / 440 us with 32x redundant x conversion).
// Fragment layouts = r15-verified (16x16x32: A lane l = A[m=l&15][k=(l>>4)*8+j],
// D lane l = D[m=(l>>4)*4+reg][n=l&15]); LDS rows padded to 80B.
//
// OCCUPANCY PIN: acc needs ~125 VGPR. r3-r8 showed the allocator spills to
// hold the LDS-limited occupancy (small LDS -> targets 8 waves/EU -> 64 VGPR
// -> scratch catastrophe). The dead-guarded 24KB pad raises LDS to ~44.5KB ->
// 3 blocks/CU = 3 waves/EU -> ~170-VGPR budget. waves_per_eu(1,3) agrees.
__global__ __attribute__((amdgpu_waves_per_eu(1, 3))) __launch_bounds__(256)
void approx_kernel(const _Float16* __restrict__ xh, const _Float16* __restrict__ kh,
                   float* __restrict__ cand_val, unsigned short* __restrict__ cand_idx) {
    const int cb = blockIdx.x, rb = blockIdx.y;
    const int col0 = cb * CBLK, row0 = rb * RBLK;
    const int tid = threadIdx.x, lane = tid & 63, w = tid >> 6;
    const int wr = w >> 1, wc = w & 1;     // wave's quadrant of the 128x128 tile

    __shared__ _Float16 ash[RBLK][40];     // 80B row stride (5x16B, banks spread)
    __shared__ _Float16 bsh[CBLK][40];
    __shared__ uint4 occ_pad[1536];        // 24KB: pins 3 blocks/CU (see above)
    if (cand_val == nullptr) occ_pad[tid] = (uint4){0u, 0u, 0u, 0u};  // never runs

    // staging: 2 threads per row, 32B each (k-halves of the 64B k-slab)
    const int srow  = tid >> 1;            // 0..127
    const int shalf = tid & 1;
    const _Float16* agp = xh + (size_t)(row0 + srow) * D_DIM + shalf * 16;
    const _Float16* bgp = kh + (size_t)(col0 + srow) * D_DIM + shalf * 16;
    _Float16* awp = &ash[srow][shalf * 16];
    _Float16* bwp = &bsh[srow][shalf * 16];

    const int mrow = lane & 15;            // row/col within a 16-frag
    const int fk   = lane >> 4;            // k-group

    f32x4 acc[4][4];
    #pragma unroll
    for (int fi = 0; fi < 4; ++fi)
        #pragma unroll
        for (int fj = 0; fj < 4; ++fj) acc[fi][fj] = (f32x4){0.f, 0.f, 0.f, 0.f};

    for (int kc = 0; kc < NKC; ++kc) {
        const int k0 = kc * KC;
        uint4 a0 = *(const uint4*)(agp + k0);
        uint4 a1 = *(const uint4*)(agp + k0 + 8);
        uint4 b0 = *(const uint4*)(bgp + k0);
        uint4 b1 = *(const uint4*)(bgp + k0 + 8);
        __syncthreads();                   // prior chunk's frag reads done
        *(uint4*)awp = a0; *(uint4*)(awp + 8) = a1;
        *(uint4*)bwp = b0; *(uint4*)(bwp + 8) = b1;
        __syncthreads();

        half8 af[4], bf[4];
        #pragma unroll
        for (int fi = 0; fi < 4; ++fi)
            af[fi] = *(const half8*)&ash[wr * 64 + fi * 16 + mrow][fk * 8];
        #pragma unroll
        for (int fj = 0; fj < 4; ++fj)
            bf[fj] = *(const half8*)&bsh[wc * 64 + fj * 16 + mrow][fk * 8];
        #pragma unroll
        for (int fi = 0; fi < 4; ++fi)
            #pragma unroll
            for (int fj = 0; fj < 4; ++fj)
                acc[fi][fj] = __builtin_amdgcn_mfma_f32_16x16x32_f16(af[fi], bf[fj], acc[fi][fj], 0, 0, 0);
    }

    // epilogue: per row top-5 over this wave's 64 cols; write set (cb*2 + wc)
    #pragma unroll
    for (int fi = 0; fi < 4; ++fi) {
        #pragma unroll
        for (int r = 0; r < 4; ++r) {
            float tv[K_SEL]; int tix[K_SEL];
            #pragma unroll
            for (int j = 0; j < K_SEL; ++j) { tv[j] = 3.0e38f; tix[j] = 0x7fffffff; }
            #pragma unroll
            for (int fj = 0; fj < 4; ++fj)
                insert5(tv, tix, 1.0f - acc[fi][fj][r],
                        col0 + wc * 64 + fj * 16 + mrow);
            #pragma unroll
            for (int off = 1; off < 16; off <<= 1) {
                float ov[K_SEL]; int oi[K_SEL];
                #pragma unroll
                for (int j = 0; j < K_SEL; ++j) {
                    ov[j] = __shfl_xor(tv[j], off, 16);
                    oi[j] = __shfl_xor(tix[j], off, 16);
                }
                #pragma unroll
                for (int j = 0; j < K_SEL; ++j) insert5(tv, tix, ov[j], oi[j]);
            }
            if (mrow == 0) {
                int grow = row0 + wr * 64 + fi * 16 + fk * 4 + r;
                #pragma unroll
                for (int j = 0; j < K_SEL; ++j) {
                    cand_val[(size_t)grow * NCAND + (cb * 2 + wc) * K_SEL + j] = tv[j];
                    cand_idx[(size_t)grow * NCAND + (cb * 2 + wc) * K_SEL + j] = (unsigned short)tix[j];
                }
            }
        }
    }
}

// Per row: rank the 160 approx candidates, exactly rescore the approx-top-16
// (fp32, sequential ascending-k, (x[k]*inv_x) rounded then FMA — the passing
// r14/r15 numerics), final top-5 by (exact value, index).
__global__ __launch_bounds__(256)
void select_rescore_kernel(const float* __restrict__ x, const float* __restrict__ kn,
                           const float* __restrict__ inv_x,
                           const float* __restrict__ cand_val,
                           const unsigned short* __restrict__ cand_idx,
                           float* __restrict__ out_dist, int* __restrict__ final_idx) {
    const int row = blockIdx.x, tid = threadIdx.x;
    __shared__ float avals[256];
    __shared__ int   aidx[256];
    __shared__ int   sel[NRESC];
    __shared__ float dsel[NRESC];

    float v = 3.0e38f; int ix = 0x7fffffff;
    if (tid < NCAND) {
        v  = cand_val[(size_t)row * NCAND + tid];
        ix = cand_idx[(size_t)row * NCAND + tid];
    }
    avals[tid] = v; aidx[tid] = ix;
    __syncthreads();
    int rank = 0;
    for (int i = 0; i < 256; ++i) {
        float ov = avals[i]; int oi = aidx[i];
        rank += (ov < v) || (ov == v && oi < ix);
    }
    if (tid < NCAND && rank < NRESC) sel[rank] = ix;   // total order -> bijective
    __syncthreads();
    if (tid < NRESC) {
        int c = sel[tid];
        float invx = inv_x[row];
        const float4* xp = (const float4*)(x + (size_t)row * D_DIM);
        const float4* bp = (const float4*)(kn + (size_t)c * D_DIM);
        float s = 0.f;
        for (int k = 0; k < D_DIM / 4; ++k) {
            float4 xv = xp[k], bv = bp[k];
            s += (xv.x * invx) * bv.x;
            s += (xv.y * invx) * bv.y;
            s += (xv.z * invx) * bv.z;
            s += (xv.w * invx) * bv.w;
        }
        dsel[tid] = 1.0f - s;
    }
    __syncthreads();
    if (tid == 0) {
        float fv[K_SEL]; int fi[K_SEL];
        #pragma unroll
        for (int j = 0; j < K_SEL; ++j) { fv[j] = 3.0e38f; fi[j] = 0x7fffffff; }
        for (int i = 0; i < NRESC; ++i) insert5(fv, fi, dsel[i], sel[i]);
        #pragma unroll
        for (int j = 0; j < K_SEL; ++j) {
            out_dist[(size_t)row * K_SEL + j] = fv[j];
            final_idx[(size_t)row * K_SEL + j] = fi[j];
        }
    }
}

// one block per (b, s): copy prompts[idx] (5*768 floats = 960 float4) to output
__global__ __launch_bounds__(256)
void gather_kernel(const float* __restrict__ prompts, const int* __restrict__ final_idx,
                   float* __restrict__ out1) {
    int bs = blockIdx.x;                 // 0 .. B_ROWS*K_SEL-1
    int p = final_idx[bs];
    const float4* src = (const float4*)(prompts + (size_t)p * (L_LEN * D_DIM));
    float4* dst = (float4*)(out1 + (size_t)bs * (L_LEN * D_DIM));
    const int n4 = (L_LEN * D_DIM) / 4;  // 960
    for (int i = threadIdx.x; i < n4; i += blockDim.x) dst[i] = src[i];
}

extern "C" void kernel_launch(void* const* d_in, const int* in_sizes, int n_in,
                              void* d_out, int out_size, void* d_ws, size_t ws_size,
                              hipStream_t stream) {
    const float* x       = (const float*)d_in[0];   // [8192, 768]
    const float* pk      = (const float*)d_in[1];   // [2048, 768]
    const float* prompts = (const float*)d_in[2];   // [2048, 5, 768]

    float* out_dist = (float*)d_out;                          // [8192, 5]
    float* out_pr   = (float*)d_out + (size_t)B_ROWS * K_SEL; // [8192, 5, 5, 768]

    char* ws = (char*)d_ws;
    float*          kn       = (float*)(ws);                      //  6,291,456 B
    _Float16*       kh       = (_Float16*)(ws + 6291456);         //  3,145,728 B
    _Float16*       xh       = (_Float16*)(ws + 9437184);         // 12,582,912 B
    float*          inv_x    = (float*)(ws + 22020096);           //     32,768 B
    float*          cand_val = (float*)(ws + 22052864);           //  5,242,880 B
    unsigned short* cand_idx = (unsigned short*)(ws + 27295744);  //  2,621,440 B
    int*            final_ix = (int*)(ws + 29917184);             //    163,840 B

    // 1) keys -> kn (fp32) + kh (fp16); x -> inv_x + xh (fp16, once)
    norm_kernel<<<(P_KEYS + B_ROWS) / 4, 256, 0, stream>>>(x, pk, kn, kh, xh, inv_x);
    // 2) fp16 MFMA approx (64x64/wave tiling) + per-row/per-64col top-5
    {
        dim3 grid(NCB2, B_ROWS / RBLK);   // (16, 64)
        approx_kernel<<<grid, 256, 0, stream>>>(xh, kh, cand_val, cand_idx);
    }
    // 3) per-row candidate ranking + exact fp32 rescore of top-16 + final top-5
    select_rescore_kernel<<<B_ROWS, 256, 0, stream>>>(x, kn, inv_x, cand_val, cand_idx,
                                                      out_dist, final_ix);
    // 4) gather prompts
    gather_kernel<<<B_ROWS * K_SEL, 256, 0, stream>>>(prompts, final_ix, out_pr);
}

// Round 17
// 712.874 us; speedup vs baseline: 1.6395x; 1.6395x over previous
//
#include <hip/hip_runtime.h>
#include <math.h>

#define B_ROWS 8192
#define P_KEYS 2048
#define D_DIM  768
#define L_LEN  5
#define K_SEL  5
#define EPSV   1e-8f

#define RBLK   64                  // rows per block (4 waves x 16)
#define CBLK   64                  // cols per block
#define NCB2   (P_KEYS / CBLK)     // 32 col blocks
#define KC     32                  // MFMA K per stage
#define NKC    (D_DIM / KC)        // 24
#define NCAND  (NCB2 * K_SEL)      // 160 candidates per row
#define NRESC  16                  // exact-rescored candidates per row

typedef _Float16 half8  __attribute__((ext_vector_type(8)));
typedef _Float16 half4v __attribute__((ext_vector_type(4)));
typedef float    f32x4  __attribute__((ext_vector_type(4)));

// sorted ascending (v[0] best). Tie-break: lower index wins (jax top_k semantics).
__device__ inline void insert5(float (&v)[K_SEL], int (&ix)[K_SEL], float nv, int ni) {
    if (nv < v[K_SEL-1] || (nv == v[K_SEL-1] && ni < ix[K_SEL-1])) {
        v[K_SEL-1] = nv; ix[K_SEL-1] = ni;
        #pragma unroll
        for (int j = K_SEL-1; j > 0; --j) {
            bool sw = (v[j] < v[j-1]) || (v[j] == v[j-1] && ix[j] < ix[j-1]);
            if (sw) {
                float tv = v[j]; v[j] = v[j-1]; v[j-1] = tv;
                int   ti = ix[j]; ix[j] = ix[j-1]; ix[j-1] = ti;
            }
        }
    }
}

// One wave per row. Keys: -> kn (fp32 normalized, exact-rescore input) and
// kh (fp16). X rows: -> inv_x AND xh = fp16(x * inv_x), precomputed once.
__global__ __launch_bounds__(256)
void norm_kernel(const float* __restrict__ x, const float* __restrict__ pk,
                 float* __restrict__ kn, _Float16* __restrict__ kh,
                 _Float16* __restrict__ xh, float* __restrict__ inv_x) {
    int wave = (blockIdx.x * blockDim.x + threadIdx.x) >> 6;
    int lane = threadIdx.x & 63;
    bool is_key = (wave < P_KEYS);
    int row = is_key ? wave : wave - P_KEYS;
    const float* src = is_key ? (pk + (size_t)row * D_DIM) : (x + (size_t)row * D_DIM);

    const float4* s4 = (const float4*)src;
    float4 v[3];
    float s = 0.f;
    #pragma unroll
    for (int i = 0; i < 3; ++i) {
        v[i] = s4[lane + 64 * i];
        s += v[i].x * v[i].x + v[i].y * v[i].y + v[i].z * v[i].z + v[i].w * v[i].w;
    }
    #pragma unroll
    for (int off = 32; off; off >>= 1) s += __shfl_xor(s, off, 64);
    float inv = 1.0f / fmaxf(sqrtf(s), EPSV);

    if (is_key) {
        float4* d4 = (float4*)(kn + (size_t)row * D_DIM);
        #pragma unroll
        for (int i = 0; i < 3; ++i) {
            float4 w = v[i];
            w.x *= inv; w.y *= inv; w.z *= inv; w.w *= inv;
            d4[lane + 64 * i] = w;
            half4v h = { (_Float16)w.x, (_Float16)w.y, (_Float16)w.z, (_Float16)w.w };
            *(half4v*)(kh + (size_t)row * D_DIM + (lane + 64 * i) * 4) = h;
        }
    } else {
        #pragma unroll
        for (int i = 0; i < 3; ++i) {
            float4 w = v[i];
            half4v h = { (_Float16)(w.x * inv), (_Float16)(w.y * inv),
                         (_Float16)(w.z * inv), (_Float16)(w.w * inv) };
            *(half4v*)(xh + (size_t)row * D_DIM + (lane + 64 * i) * 4) = h;
        }
        if (lane == 0) inv_x[row] = inv;
    }
}

// Approx pass v3: fp16 MFMA, LOW-PRESSURE wave tile.
// r16 lesson: acc[4][4] (64 VGPR) + frags blew the allocator's will (96 VGPR,
// 1.2 GB scratch, MfmaUtil 1.2%); the LDS occ-pad was DCE'd and waves_per_eu
// ignored. Design rule from r9/r14 (56 VGPR, no spill): keep live state <=64.
// Wave tile = 16 rows x 64 cols: 1 A-frag x 4 B-frags -> acc = 4xf32x4 = 16
// VGPR, ~50 total. Block 256 = 4 waves stacked in rows (64x64 tile); grid
// (32 cb, 128 rb) = 4096 blocks. Per kc: 5 ds_read_b128 + 4 MFMA per wave.
// Fragment layouts r15/r16-verified: A lane l = A[m=l&15][k=(l>>4)*8+j],
// B lane l = B[k=(l>>4)*8+j][n=l&15], D lane l = D[m=(l>>4)*4+r][n=l&15].
__global__ __launch_bounds__(256)
void approx_kernel(const _Float16* __restrict__ xh, const _Float16* __restrict__ kh,
                   float* __restrict__ cand_val, unsigned short* __restrict__ cand_idx) {
    const int cb = blockIdx.x, rb = blockIdx.y;
    const int col0 = cb * CBLK, row0 = rb * RBLK;
    const int tid = threadIdx.x, lane = tid & 63, w = tid >> 6;

    __shared__ _Float16 ash[RBLK][40];     // 80B row stride (<=2-way aliasing)
    __shared__ _Float16 bsh[CBLK][40];     // 10 KB total

    // staging: thread t -> row t>>2 (0..63), k-quad t&3 (8 fp16 = 16B) of A and B
    const int srow = tid >> 2, skq = tid & 3;
    const _Float16* agp = xh + (size_t)(row0 + srow) * D_DIM + skq * 8;
    const _Float16* bgp = kh + (size_t)(col0 + srow) * D_DIM + skq * 8;

    const int mrow = lane & 15;            // m (A) / n (B) within a 16-frag
    const int fk   = lane >> 4;            // k-group

    f32x4 acc[4];
    #pragma unroll
    for (int fj = 0; fj < 4; ++fj) acc[fj] = (f32x4){0.f, 0.f, 0.f, 0.f};

    for (int kc = 0; kc < NKC; ++kc) {
        const int k0 = kc * KC;
        uint4 av = *(const uint4*)(agp + k0);
        uint4 bv = *(const uint4*)(bgp + k0);
        __syncthreads();                   // prior chunk's frag reads done
        *(uint4*)&ash[srow][skq * 8] = av;
        *(uint4*)&bsh[srow][skq * 8] = bv;
        __syncthreads();

        half8 a = *(const half8*)&ash[w * 16 + mrow][fk * 8];
        #pragma unroll
        for (int fj = 0; fj < 4; ++fj) {
            half8 b = *(const half8*)&bsh[fj * 16 + mrow][fk * 8];
            acc[fj] = __builtin_amdgcn_mfma_f32_16x16x32_f16(a, b, acc[fj], 0, 0, 0);
        }
    }

    // epilogue: lane holds D[m=(lane>>4)*4+r][n=lane&15] per fj tile
    #pragma unroll
    for (int r = 0; r < 4; ++r) {
        float tv[K_SEL]; int tix[K_SEL];
        #pragma unroll
        for (int j = 0; j < K_SEL; ++j) { tv[j] = 3.0e38f; tix[j] = 0x7fffffff; }
        #pragma unroll
        for (int fj = 0; fj < 4; ++fj)
            insert5(tv, tix, 1.0f - acc[fj][r], col0 + fj * 16 + mrow);
        #pragma unroll
        for (int off = 1; off < 16; off <<= 1) {
            float ov[K_SEL]; int oi[K_SEL];
            #pragma unroll
            for (int j = 0; j < K_SEL; ++j) {
                ov[j] = __shfl_xor(tv[j], off, 16);
                oi[j] = __shfl_xor(tix[j], off, 16);
            }
            #pragma unroll
            for (int j = 0; j < K_SEL; ++j) insert5(tv, tix, ov[j], oi[j]);
        }
        if (mrow == 0) {
            int grow = row0 + w * 16 + fk * 4 + r;
            #pragma unroll
            for (int j = 0; j < K_SEL; ++j) {
                cand_val[(size_t)grow * NCAND + cb * K_SEL + j] = tv[j];
                cand_idx[(size_t)grow * NCAND + cb * K_SEL + j] = (unsigned short)tix[j];
            }
        }
    }
}

// Per row: rank the 160 approx candidates, exactly rescore the approx-top-16
// (fp32, sequential ascending-k, (x[k]*inv_x) rounded then FMA — the passing
// r14/r15/r16 numerics), final top-5 by (exact value, index).
__global__ __launch_bounds__(256)
void select_rescore_kernel(const float* __restrict__ x, const float* __restrict__ kn,
                           const float* __restrict__ inv_x,
                           const float* __restrict__ cand_val,
                           const unsigned short* __restrict__ cand_idx,
                           float* __restrict__ out_dist, int* __restrict__ final_idx) {
    const int row = blockIdx.x, tid = threadIdx.x;
    __shared__ float avals[256];
    __shared__ int   aidx[256];
    __shared__ int   sel[NRESC];
    __shared__ float dsel[NRESC];

    float v = 3.0e38f; int ix = 0x7fffffff;
    if (tid < NCAND) {
        v  = cand_val[(size_t)row * NCAND + tid];
        ix = cand_idx[(size_t)row * NCAND + tid];
    }
    avals[tid] = v; aidx[tid] = ix;
    __syncthreads();
    int rank = 0;
    for (int i = 0; i < 256; ++i) {
        float ov = avals[i]; int oi = aidx[i];
        rank += (ov < v) || (ov == v && oi < ix);
    }
    if (tid < NCAND && rank < NRESC) sel[rank] = ix;   // total order -> bijective
    __syncthreads();
    if (tid < NRESC) {
        int c = sel[tid];
        float invx = inv_x[row];
        const float4* xp = (const float4*)(x + (size_t)row * D_DIM);
        const float4* bp = (const float4*)(kn + (size_t)c * D_DIM);
        float s = 0.f;
        for (int k = 0; k < D_DIM / 4; ++k) {
            float4 xv = xp[k], bv = bp[k];
            s += (xv.x * invx) * bv.x;
            s += (xv.y * invx) * bv.y;
            s += (xv.z * invx) * bv.z;
            s += (xv.w * invx) * bv.w;
        }
        dsel[tid] = 1.0f - s;
    }
    __syncthreads();
    if (tid == 0) {
        float fv[K_SEL]; int fi[K_SEL];
        #pragma unroll
        for (int j = 0; j < K_SEL; ++j) { fv[j] = 3.0e38f; fi[j] = 0x7fffffff; }
        for (int i = 0; i < NRESC; ++i) insert5(fv, fi, dsel[i], sel[i]);
        #pragma unroll
        for (int j = 0; j < K_SEL; ++j) {
            out_dist[(size_t)row * K_SEL + j] = fv[j];
            final_idx[(size_t)row * K_SEL + j] = fi[j];
        }
    }
}

// one block per (b, s): copy prompts[idx] (5*768 floats = 960 float4) to output
__global__ __launch_bounds__(256)
void gather_kernel(const float* __restrict__ prompts, const int* __restrict__ final_idx,
                   float* __restrict__ out1) {
    int bs = blockIdx.x;                 // 0 .. B_ROWS*K_SEL-1
    int p = final_idx[bs];
    const float4* src = (const float4*)(prompts + (size_t)p * (L_LEN * D_DIM));
    float4* dst = (float4*)(out1 + (size_t)bs * (L_LEN * D_DIM));
    const int n4 = (L_LEN * D_DIM) / 4;  // 960
    for (int i = threadIdx.x; i < n4; i += blockDim.x) dst[i] = src[i];
}

extern "C" void kernel_launch(void* const* d_in, const int* in_sizes, int n_in,
                              void* d_out, int out_size, void* d_ws, size_t ws_size,
                              hipStream_t stream) {
    const float* x       = (const float*)d_in[0];   // [8192, 768]
    const float* pk      = (const float*)d_in[1];   // [2048, 768]
    const float* prompts = (const float*)d_in[2];   // [2048, 5, 768]

    float* out_dist = (float*)d_out;                          // [8192, 5]
    float* out_pr   = (float*)d_out + (size_t)B_ROWS * K_SEL; // [8192, 5, 5, 768]

    char* ws = (char*)d_ws;
    float*          kn       = (float*)(ws);                      //  6,291,456 B
    _Float16*       kh       = (_Float16*)(ws + 6291456);         //  3,145,728 B
    _Float16*       xh       = (_Float16*)(ws + 9437184);         // 12,582,912 B
    float*          inv_x    = (float*)(ws + 22020096);           //     32,768 B
    float*          cand_val = (float*)(ws + 22052864);           //  5,242,880 B
    unsigned short* cand_idx = (unsigned short*)(ws + 27295744);  //  2,621,440 B
    int*            final_ix = (int*)(ws + 29917184);             //    163,840 B

    // 1) keys -> kn (fp32) + kh (fp16); x -> inv_x + xh (fp16, once)
    norm_kernel<<<(P_KEYS + B_ROWS) / 4, 256, 0, stream>>>(x, pk, kn, kh, xh, inv_x);
    // 2) fp16 MFMA approx (16x64/wave, low-pressure) + per-row/per-64col top-5
    {
        dim3 grid(NCB2, B_ROWS / RBLK);   // (32, 128)
        approx_kernel<<<grid, 256, 0, stream>>>(xh, kh, cand_val, cand_idx);
    }
    // 3) per-row candidate ranking + exact fp32 rescore of top-16 + final top-5
    select_rescore_kernel<<<B_ROWS, 256, 0, stream>>>(x, kn, inv_x, cand_val, cand_idx,
                                                      out_dist, final_ix);
    // 4) gather prompts
    gather_kernel<<<B_ROWS * K_SEL, 256, 0, stream>>>(prompts, final_ix, out_pr);
}